// Round 7
// baseline (328.224 us; speedup 1.0000x reference)
//
#include <hip/hip_runtime.h>
#include <math.h>

// Round 7: fix P2's duty-cycle collapse (ledger-fit: 1-block/CU LDS-monolith
// streams at 2.6 TB/s vs 5.7 TB/s for multi-block/CU — R2 rows_kernel evidence).
//  P1 (unchanged core): 391 blocks x 1024, bin 4096 pairs -> stage[2048 4-row
//     buckets][8] sentinel-padded 64B slots -> region1; LDS overflow (~68/blk)
//     flushed to per-2-row-band L2-resident lists (4096 cursors = 256 lines,
//     ~6 atomics/line — no hot-line serialization).
//  P2: 4096 blocks x 512, 64 KiB LDS (2 rows) => 2 blocks/CU. Gather parent
//     4-row slice (25KB, filter key>>14==band2), drain own ovf list, diag,
//     stream 64 KiB out coalesced. Zero global atomics anywhere on main path.
//  Dispatches: memset(hdr) + p1 + p2  (was 4 kernels).
// entry = uint2{ key=(row<<13)|col, f32 bits }, SENT key=all-ones (>>14 = 0x3FFFF
// never matches band2<4096). d=2^13 -> flat out index == key.

#define P1_PAIRS 4096
#define NBKT     2048          // 4-row buckets (P1 stage granularity)
#define BCAP     8             // slot = 64B line
#define NB2      4096          // 2-row bands (P2 granularity)
#define OVB      512           // per-P1-block LDS overflow buffer
#define OVCAP    64            // per-band overflow list capacity
#define SENTK    0xFFFFFFFFu
#define GCAP     65536

// ---------------------------------------------------------------- fused path

__global__ __launch_bounds__(1024) void p1_kernel(
    const int*   __restrict__ idx,     // [2, M] int32
    const float* __restrict__ vals,    // [M]
    float scale, int m, int nblk,
    uint2* __restrict__ region1,       // [NBKT][nblk][BCAP]
    uint2* __restrict__ ovfreg,        // [NB2][OVCAP]
    int*   __restrict__ ovfcur,        // [NB2]
    uint2* __restrict__ glist,         // [GCAP] never-path
    int*   __restrict__ ghdr)
{
    __shared__ uint2 stage[NBKT][BCAP];    // 128 KiB
    __shared__ int   cnt[NBKT];            // 8 KiB
    __shared__ uint2 ovfst[OVB];           // 4 KiB
    __shared__ int   ovfn;

    uint2* sflat = &stage[0][0];
    for (int f = threadIdx.x; f < NBKT * BCAP; f += 1024)
        sflat[f] = make_uint2(SENTK, 0u);
    for (int b = threadIdx.x; b < NBKT; b += 1024) cnt[b] = 0;
    if (threadIdx.x == 0) ovfn = 0;
    __syncthreads();

    const int blk  = blockIdx.x;
    const int base = blk * P1_PAIRS;
#pragma unroll
    for (int it = 0; it < P1_PAIRS / 1024; ++it) {
        int k = base + it * 1024 + threadIdx.x;
        if (k < m) {
            int i = idx[k];
            int j = idx[m + k];
            unsigned vb = __float_as_uint(vals[k] * scale);

            unsigned k1 = ((unsigned)i << 13) | (unsigned)j;
            int b1 = i >> 2;
            int p = atomicAdd(&cnt[b1], 1);
            if (p < BCAP) stage[b1][p] = make_uint2(k1, vb);
            else { int q = atomicAdd(&ovfn, 1);
                   if (q < OVB) ovfst[q] = make_uint2(k1, vb);
                   else { int g = atomicAdd(ghdr, 1); if (g < GCAP) glist[g] = make_uint2(k1, vb); } }

            unsigned k2 = ((unsigned)j << 13) | (unsigned)i;
            int b2 = j >> 2;
            p = atomicAdd(&cnt[b2], 1);
            if (p < BCAP) stage[b2][p] = make_uint2(k2, vb);
            else { int q = atomicAdd(&ovfn, 1);
                   if (q < OVB) ovfst[q] = make_uint2(k2, vb);
                   else { int g = atomicAdd(ghdr, 1); if (g < GCAP) glist[g] = make_uint2(k2, vb); } }
        }
    }
    __syncthreads();

    // flush slots: each bucket's 8 entries = one aligned 64B line burst
    for (int f = threadIdx.x; f < NBKT * BCAP; f += 1024) {
        int b = f >> 3, e = f & 7;
        region1[((long long)b * nblk + blk) * BCAP + e] = sflat[f];
    }
    // flush LDS overflow to per-band L2-resident lists (4096 counters = 256 lines)
    int n = ovfn; if (n > OVB) n = OVB;
    for (int e = threadIdx.x; e < n; e += 1024) {
        uint2 en = ovfst[e];
        int band2 = en.x >> 14;
        int pos = atomicAdd(&ovfcur[band2], 1);
        if (pos < OVCAP) ovfreg[band2 * OVCAP + pos] = en;
        else { int g = atomicAdd(ghdr, 1); if (g < GCAP) glist[g] = en; }
    }
}

__global__ __launch_bounds__(512) void p2_kernel(
    float* __restrict__ out,
    const float* __restrict__ h_local,
    const uint2* __restrict__ region1,
    int nblk,
    const uint2* __restrict__ ovfreg,
    const int*   __restrict__ ovfcur,
    const uint2* __restrict__ glist,
    const int*   __restrict__ ghdr)
{
    __shared__ float srow[2 * 8192];               // 64 KiB: 2 rows -> 2 blocks/CU
    float4* s4 = reinterpret_cast<float4*>(srow);
    const int band2 = blockIdx.x;                  // rows 2*band2, 2*band2+1

    for (int c = threadIdx.x; c < 4096; c += 512)
        s4[c] = make_float4(0.f, 0.f, 0.f, 0.f);
    __syncthreads();

    // gather parent 4-row bucket slice (25KB contiguous), filter to our 2 rows
    const uint4* src = reinterpret_cast<const uint4*>(
        region1 + (long long)(band2 >> 1) * nblk * BCAP);
    const int n2 = (nblk * BCAP) >> 1;
    const unsigned bu = (unsigned)band2;
    for (int e = threadIdx.x; e < n2; e += 512) {
        uint4 en = src[e];
        if ((en.x >> 14) == bu) srow[en.x & 16383] = __uint_as_float(en.y);
        if ((en.z >> 14) == bu) srow[en.z & 16383] = __uint_as_float(en.w);
    }
    // drain own overflow list (L2-resident, ~6 entries expected)
    int n = ovfcur[band2]; if (n > OVCAP) n = OVCAP;
    for (int e = threadIdx.x; e < n; e += 512) {
        uint2 en = ovfreg[band2 * OVCAP + e];
        srow[en.x & 16383] = __uint_as_float(en.y);
    }
    // never-path spill
    int gn = ghdr[0];
    if (gn > 0) {
        if (gn > GCAP) gn = GCAP;
        for (int e = threadIdx.x; e < gn; e += 512) {
            uint2 en = glist[e];
            if ((en.x >> 14) == bu) srow[en.x & 16383] = __uint_as_float(en.y);
        }
    }
    if (threadIdx.x < 2) {
        int r = (band2 << 1) + threadIdx.x;
        srow[((unsigned)threadIdx.x << 13) | (unsigned)r] = h_local[r];
    }
    __syncthreads();

    float4* orow = reinterpret_cast<float4*>(out + ((long long)band2 << 14));
    for (int c = threadIdx.x; c < 4096; c += 512)
        orow[c] = s4[c];
}

// ---------------------------------------------------------------- fallbacks

__global__ __launch_bounds__(256) void init_counts_kernel(
    float* __restrict__ out, int d, int logd)
{
    int r = blockIdx.x * blockDim.x + threadIdx.x;
    if (r < d) reinterpret_cast<int*>(out)[(long long)r << logd] = 0;
}

__global__ __launch_bounds__(256) void bin_kernel(
    float* __restrict__ out,
    const int*   __restrict__ idx,
    const float* __restrict__ vals,
    float scale, int m, int logd, int cap)
{
    int k = blockIdx.x * blockDim.x + threadIdx.x;
    if (k >= m) return;
    int i = idx[k];
    int j = idx[m + k];
    unsigned vb = __float_as_uint(vals[k] * scale);
    int* cnt_i = reinterpret_cast<int*>(out) + ((long long)i << logd);
    int* cnt_j = reinterpret_cast<int*>(out) + ((long long)j << logd);
    int p1 = atomicAdd(cnt_i, 1);
    if (p1 < cap)
        *reinterpret_cast<uint2*>(out + ((long long)i << logd) + 2 + 2 * p1) =
            make_uint2((unsigned)j, vb);
    int p2 = atomicAdd(cnt_j, 1);
    if (p2 < cap)
        *reinterpret_cast<uint2*>(out + ((long long)j << logd) + 2 + 2 * p2) =
            make_uint2((unsigned)i, vb);
}

__global__ __launch_bounds__(256) void rows_kernel(
    float* __restrict__ out,
    const float* __restrict__ h_local,
    int logd, int cap)
{
    __shared__ float srow[8192];
    const int d  = 1 << logd;
    const int n4 = d >> 2;
    float4* s4 = reinterpret_cast<float4*>(srow);
    const int r = blockIdx.x;
    float* grow = out + ((long long)r << logd);
    const float4 z = make_float4(0.f, 0.f, 0.f, 0.f);
    for (int c = threadIdx.x; c < n4; c += blockDim.x) s4[c] = z;
    __syncthreads();
    int cnt = reinterpret_cast<const int*>(grow)[0];
    if (cnt > cap) cnt = cap;
    const uint2* eb = reinterpret_cast<const uint2*>(grow + 2);
    for (int e = threadIdx.x; e < cnt; e += blockDim.x) {
        uint2 p = eb[e];
        srow[p.x] = __uint_as_float(p.y);
    }
    if (threadIdx.x == 0) srow[r] = h_local[r];
    __syncthreads();
    for (int c = threadIdx.x; c < n4; c += blockDim.x)
        reinterpret_cast<float4*>(grow)[c] = s4[c];
}

__global__ __launch_bounds__(256) void fill_diag_kernel(
    float* __restrict__ out, const float* __restrict__ h_local,
    int d, long long n)
{
    long long t = (long long)blockIdx.x * blockDim.x + threadIdx.x;
    if (t >= n) return;
    long long row = t / d;
    long long col = t - row * d;
    out[t] = (row == col) ? h_local[row] : 0.f;
}

__global__ __launch_bounds__(256) void scatter_kernel(
    float* __restrict__ out,
    const int* __restrict__ idx,
    const float* __restrict__ vals,
    float scale, int m, int d)
{
    int k = blockIdx.x * blockDim.x + threadIdx.x;
    if (k >= m) return;
    int i = idx[k];
    int j = idx[m + k];
    float v = vals[k] * scale;
    out[(long long)i * d + j] = v;
    out[(long long)j * d + i] = v;
}

// ---------------------------------------------------------------- launch

extern "C" void kernel_launch(void* const* d_in, const int* in_sizes, int n_in,
                              void* d_out, int out_size, void* d_ws, size_t ws_size,
                              hipStream_t stream) {
    const float* h_local = (const float*)d_in[0];
    const float* V_int   = (const float*)d_in[1];
    const int*   idx     = (const int*)d_in[2];

    const int d = in_sizes[0];            // 8192
    const int m = in_sizes[1];            // 1,600,000

    int logd = 0;
    while ((1 << logd) < d) ++logd;
    const bool pow2 = ((1 << logd) == d);

    const float iscale = (float)(1.0 - 0.2 / sqrt(log((double)d)));
    float* out = (float*)d_out;
    const int block = 256;

    const int nblk = (m + P1_PAIRS - 1) / P1_PAIRS;      // 391 for m=1.6M

    // ws layout: [ghdr @0][ovfcur @4096: NB2*4=16KB] -> memset first 20.5KB
    //            [glist 512KB][ovfreg 2MB][region1 ~51MB]
    const size_t off_ovfcur = 4096;
    const size_t hdr_bytes  = off_ovfcur + (size_t)NB2 * 4;          // 20480
    const size_t off_glist  = 24576;
    const size_t off_ovfreg = off_glist + (size_t)GCAP * sizeof(uint2);
    const size_t off_r1     = off_ovfreg + (size_t)NB2 * OVCAP * sizeof(uint2);
    const size_t ws_need    = off_r1 + (size_t)NBKT * nblk * BCAP * sizeof(uint2);

    const bool path7 = (d == 8192) && (m > 0) && (m <= 2000000) &&
                       (d_ws != nullptr) && (ws_size >= ws_need);

    if (path7) {
        char* ws = (char*)d_ws;
        int*   ghdr    = (int*)ws;
        int*   ovfcur  = (int*)(ws + off_ovfcur);
        uint2* glist   = (uint2*)(ws + off_glist);
        uint2* ovfreg  = (uint2*)(ws + off_ovfreg);
        uint2* region1 = (uint2*)(ws + off_r1);

        hipMemsetAsync(ws, 0, hdr_bytes, stream);
        p1_kernel<<<nblk, 1024, 0, stream>>>(idx, V_int, iscale, m, nblk,
                                             region1, ovfreg, ovfcur, glist, ghdr);
        p2_kernel<<<NB2, 512, 0, stream>>>(out, h_local, region1, nblk,
                                           ovfreg, ovfcur, glist, ghdr);
    } else if (pow2 && d >= 1024 && d <= 8192 &&
               ((long long)m * 2 / d) < (long long)((d - 2) / 2) / 2) {
        const int cap = (d - 2) / 2;
        init_counts_kernel<<<(d + block - 1) / block, block, 0, stream>>>(out, d, logd);
        bin_kernel<<<(m + block - 1) / block, block, 0, stream>>>(out, idx, V_int,
                                                                  iscale, m, logd, cap);
        rows_kernel<<<d, block, 0, stream>>>(out, h_local, logd, cap);
    } else {
        const long long n = (long long)d * d;
        const long long grid_fill = (n + block - 1) / block;
        fill_diag_kernel<<<(dim3)(unsigned)grid_fill, block, 0, stream>>>(out, h_local, d, n);
        const int grid_sc = (m + block - 1) / block;
        scatter_kernel<<<grid_sc, block, 0, stream>>>(out, idx, V_int, iscale, m, d);
    }
}